// Round 2
// baseline (72.882 us; speedup 1.0000x reference)
//
#include <hip/hip_runtime.h>
#include <hip/hip_bf16.h>

// GaussianImage / Cholesky sum-rasterizer, T=3 frames, N=2000 gaussians, 256x256.
// Two kernels: (1) per-gaussian preprocess -> workspace params+cull bbox,
// (2) tile-based gather render with LDS compaction of tile-intersecting gaussians.
//
// Sparsity argument: Sigma ~= I, opac ~= 0.5 -> alpha >= 1/255 inside
// q <= 2*ln(255*opac) ~= 9.7 -> ~3px radius -> ~15-30 survivors per 16x16 tile.

#define TFRAMES 3
#define NG      2000
#define HH      256
#define WW      256
#define ALPHA_THRESH (1.0f / 255.0f)
#define ALPHA_CLAMP  0.999f

__device__ __forceinline__ float sigmoidf_(float x) { return 1.0f / (1.0f + expf(-x)); }

// ws layout (float4 arrays, [t*NG + n]):
//   cull[idx] = (mx, my, rx, ry)       rx<0 => never contributes
//   g1[idx]   = (conA, conB, conC, opac)
//   g2[idx]   = (cr, cg, cb, unused)
// total = 3 * T*N * 16B = 288000 bytes of d_ws (fully rewritten every launch).

__global__ void gs_preprocess(const float* __restrict__ xyz,
                              const float* __restrict__ chol,
                              const float* __restrict__ opc,
                              const float* __restrict__ feat,
                              float4* __restrict__ cull,
                              float4* __restrict__ g1,
                              float4* __restrict__ g2)
{
    int n = blockIdx.x * blockDim.x + threadIdx.x;
    if (n >= NG) return;

    float cxc[3], cyc[3], l1c[3], l2c[3], l3c[3], opcc[3];
#pragma unroll
    for (int d = 0; d < 3; ++d) {
        cxc[d]  = xyz[(d * NG + n) * 2 + 0];
        cyc[d]  = xyz[(d * NG + n) * 2 + 1];
        l1c[d]  = chol[(d * NG + n) * 3 + 0];
        l2c[d]  = chol[(d * NG + n) * 3 + 1];
        l3c[d]  = chol[(d * NG + n) * 3 + 2];
        opcc[d] = opc[d * NG + n];
    }
    float cr = sigmoidf_(feat[n * 3 + 0]);
    float cg = sigmoidf_(feat[n * 3 + 1]);
    float cb = sigmoidf_(feat[n * 3 + 2]);

#pragma unroll
    for (int t = 0; t < TFRAMES; ++t) {
        float tv = (float)t / (float)(TFRAMES - 1);   // 0, 0.5, 1
        // Horner == sum_d c[d]*t^d (poly eval at t; matches einsum with [1,t,t^2])
        float vx = fmaf(tv, fmaf(tv, cxc[2], cxc[1]), cxc[0]);
        float vy = fmaf(tv, fmaf(tv, cyc[2], cyc[1]), cyc[0]);
        float l1 = fmaf(tv, fmaf(tv, l1c[2], l1c[1]), l1c[0]) + 0.5f;
        float l2 = fmaf(tv, fmaf(tv, l2c[2], l2c[1]), l2c[0]);
        float l3 = fmaf(tv, fmaf(tv, l3c[2], l3c[1]), l3c[0]) + 0.5f;
        float po = fmaf(tv, fmaf(tv, opcc[2], opcc[1]), opcc[0]);

        float mx = 128.0f * (tanhf(vx) + 1.0f);   // 0.5*W*(x+1), W=H=256
        float my = 128.0f * (tanhf(vy) + 1.0f);

        // Sigma = L L^T, L=[[l1,0],[l2,l3]]
        float a = l1 * l1;
        float b = l1 * l2;
        float c = l2 * l2 + l3 * l3;
        float det = a * c - b * b;              // = (l1*l3)^2 >= 0
        float opa = sigmoidf_(po);

        float rx = -1.0e9f, ry = -1.0e9f;
        float A = 0.f, B = 0.f, C = 0.f;
        if (det > 0.0f && det < 3.0e38f) {
            float inv = 1.0f / det;
            A = c * inv;            // conic = Sigma^{-1}
            B = -b * inv;
            C = a * inv;
            float s = opa * 255.0f;
            if (s > 1.0f) {
                // alpha >= 1/255  <=>  q <= 2*ln(255*opac); inflate conservatively
                // so fp rounding can never EXCLUDE a pixel the reference includes.
                float qm  = 2.0f * logf(s);
                float qmc = fmaf(qm, 1.0001f, 1e-3f);
                rx = sqrtf(qmc * a);   // ellipse x-extent = sqrt(qm * Sigma_xx)
                ry = sqrtf(qmc * c);   // ellipse y-extent = sqrt(qm * Sigma_yy)
            }
        }
        int idx = t * NG + n;
        cull[idx] = make_float4(mx, my, rx, ry);
        g1[idx]   = make_float4(A, B, C, opa);
        g2[idx]   = make_float4(cr, cg, cb, 0.0f);
    }
}

__global__ __launch_bounds__(256) void gs_render(const float4* __restrict__ cull,
                                                 const float4* __restrict__ g1,
                                                 const float4* __restrict__ g2,
                                                 float* __restrict__ out)
{
    const int tid = threadIdx.x;
    const int tx  = tid & 15;
    const int ty  = tid >> 4;
    const int px  = (blockIdx.x << 4) + tx;
    const int py  = (blockIdx.y << 4) + ty;
    const int t   = blockIdx.z;
    const float tcx = (float)(blockIdx.x << 4) + 7.5f;  // tile center (pixels at int coords)
    const float tcy = (float)(blockIdx.y << 4) + 7.5f;

    __shared__ int    s_cnt;
    __shared__ float2 s_pos[256];
    __shared__ float4 s_A[256];
    __shared__ float4 s_C[256];

    const float4* __restrict__ cu = cull + t * NG;
    const float4* __restrict__ gA = g1   + t * NG;
    const float4* __restrict__ gC = g2   + t * NG;

    float accr = 0.f, accg = 0.f, accb = 0.f;
    const float fx = (float)px, fy = (float)py;

    for (int base = 0; base < NG; base += 256) {
        if (tid == 0) s_cnt = 0;
        __syncthreads();

        int g = base + tid;
        if (g < NG) {
            float4 c4 = cu[g];
            // conservative tile/bbox overlap: |mx - tile_cx| <= rx + 7.5
            if (fabsf(c4.x - tcx) <= c4.z + 7.5f &&
                fabsf(c4.y - tcy) <= c4.w + 7.5f) {
                int k = atomicAdd(&s_cnt, 1);   // <=256 writers per chunk, no overflow
                s_pos[k] = make_float2(c4.x, c4.y);
                s_A[k]   = gA[g];
                s_C[k]   = gC[g];
            }
        }
        __syncthreads();

        int cnt = s_cnt;
        for (int j = 0; j < cnt; ++j) {
            float2 p = s_pos[j];            // same-address LDS broadcast: conflict-free
            float4 A = s_A[j];
            float dx = p.x - fx;
            float dy = p.y - fy;
            // q exactly as reference: a*dx^2 + 2b*dx*dy + c*dy^2, then exp(-0.5q)
            float q = A.x * dx * dx + 2.0f * A.y * dx * dy + A.z * dy * dy;
            float alpha = fminf(ALPHA_CLAMP, A.w * expf(-0.5f * q));
            float w = (alpha >= ALPHA_THRESH) ? alpha : 0.0f;  // kernel skip, branchless
            float4 col = s_C[j];
            accr = fmaf(w, col.x, accr);
            accg = fmaf(w, col.y, accg);
            accb = fmaf(w, col.z, accb);
        }
        __syncthreads();   // protect LDS before next chunk overwrites
    }

    // out[T,3,H,W]: final clip to [0,1] as in reference
    size_t o = (size_t)t * 3 * HH * WW + (size_t)py * WW + px;
    out[o]                        = fminf(fmaxf(accr, 0.f), 1.f);
    out[o + (size_t)HH * WW]      = fminf(fmaxf(accg, 0.f), 1.f);
    out[o + (size_t)2 * HH * WW]  = fminf(fmaxf(accb, 0.f), 1.f);
}

extern "C" void kernel_launch(void* const* d_in, const int* in_sizes, int n_in,
                              void* d_out, int out_size, void* d_ws, size_t ws_size,
                              hipStream_t stream)
{
    const float* xyz  = (const float*)d_in[0];   // [3, N, 2]
    const float* chol = (const float*)d_in[1];   // [3, N, 3]
    const float* opc  = (const float*)d_in[2];   // [3, N, 1]
    const float* feat = (const float*)d_in[3];   // [N, 3]
    float* out = (float*)d_out;                  // [T, 3, H, W] fp32

    char* ws = (char*)d_ws;
    float4* cull = (float4*)(ws);
    float4* g1   = (float4*)(ws + (size_t)TFRAMES * NG * 16);
    float4* g2   = (float4*)(ws + (size_t)2 * TFRAMES * NG * 16);

    gs_preprocess<<<dim3((NG + 255) / 256), dim3(256), 0, stream>>>(
        xyz, chol, opc, feat, cull, g1, g2);

    gs_render<<<dim3(WW / 16, HH / 16, TFRAMES), dim3(256), 0, stream>>>(
        cull, g1, g2, out);
}